// Round 5
// baseline (418.785 us; speedup 1.0000x reference)
//
#include <hip/hip_runtime.h>
#include <hip/hip_bf16.h>

#define E 256
#define H 16
#define DD 16
#define FFH 512
#define LAYERS 5
#define BB 4
#define NN 256
#define MROWS 1024  // B*N

typedef __attribute__((ext_vector_type(8))) short bfrag;
typedef __attribute__((ext_vector_type(4))) float f32x4;
typedef __attribute__((ext_vector_type(8))) unsigned short us8;
typedef unsigned short u16;

__device__ __forceinline__ void bsplit(float v, u16& h, u16& l) {
    unsigned u = __float_as_uint(v);
    u16 hh = (u16)((u + 0x7fffu + ((u >> 16) & 1u)) >> 16);
    float r = v - __uint_as_float((unsigned)hh << 16);
    unsigned u2 = __float_as_uint(r);
    h = hh;
    l = (u16)((u2 + 0x7fffu + ((u2 >> 16) & 1u)) >> 16);
}

// ================= fused prep (minmax | emb | dataT | wprep | mixconst) =================
union PrepS {
    float tile[32 * 33];
    struct { u16 th[64 * 40], tl[64 * 40]; } wp;
    struct { float smin[4], smax[4]; } mm;
};

__global__ __launch_bounds__(256) void k_prep(
    const float* __restrict__ data, const float* __restrict__ node_rand,
    const float* __restrict__ Wnode, const float* __restrict__ bnode,
    const float* __restrict__ Wedge, const float* __restrict__ bedge,
    const float* __restrict__ Wmix,
    const float* __restrict__ Wq, const float* __restrict__ Wk, const float* __restrict__ Wv,
    const float* __restrict__ Wc, const float* __restrict__ W1, const float* __restrict__ W2,
    float* __restrict__ pmin, float* __restrict__ pmax, float* __restrict__ c1c0,
    float* __restrict__ rowb, float* __restrict__ colb,
    u16* rowh, u16* rowl, u16* colh, u16* coll,
    float* __restrict__ dataT,
    u16* qh, u16* ql, u16* kh, u16* kl_, u16* vh, u16* vl,
    u16* ch, u16* cl, u16* f1h, u16* f1l, u16* f2h, u16* f2l) {
    __shared__ PrepS ps;
    int bid = blockIdx.x;
    int t = threadIdx.x;
    if (bid < 64) {
        // minmax stage-1 partials
        int b = bid >> 4, p = bid & 15;
        const float* src = data + (size_t)b * NN * NN + p * 4096;
        float lmin = 1e30f, lmax = -1e30f;
        #pragma unroll
        for (int i = 0; i < 16; i++) {
            float v = src[t + i * 256];
            lmin = fminf(lmin, v);
            lmax = fmaxf(lmax, v);
        }
        #pragma unroll
        for (int off = 32; off; off >>= 1) {
            lmin = fminf(lmin, __shfl_down(lmin, off));
            lmax = fmaxf(lmax, __shfl_down(lmax, off));
        }
        int wid = t >> 6, lane = t & 63;
        if (lane == 0) { ps.mm.smin[wid] = lmin; ps.mm.smax[wid] = lmax; }
        __syncthreads();
        if (t == 0) {
            pmin[b * 16 + p] = fminf(fminf(ps.mm.smin[0], ps.mm.smin[1]), fminf(ps.mm.smin[2], ps.mm.smin[3]));
            pmax[b * 16 + p] = fmaxf(fmaxf(ps.mm.smax[0], ps.mm.smax[1]), fmaxf(ps.mm.smax[2], ps.mm.smax[3]));
        }
    } else if (bid < 1088) {
        int idx = (bid - 64) * 256 + t;
        int bn = idx >> 8, e = idx & 255;
        float v = node_rand[bn] * Wnode[e] + bnode[e];
        rowb[idx] = v;
        colb[idx] = v;
        u16 h, l;
        bsplit(v, h, l);
        rowh[idx] = h; rowl[idx] = l;
        colh[idx] = h; coll[idx] = l;
    } else if (bid < 1344) {
        int local = bid - 1088;
        int bx = local & 7, by = (local >> 3) & 7, b = local >> 6;
        int r0 = by * 32, c0 = bx * 32;
        int tx = t & 31, ty = t >> 5;
        const float* src = data + (size_t)b * NN * NN;
        float* dst = dataT + (size_t)b * NN * NN;
        #pragma unroll
        for (int i = 0; i < 4; i++)
            ps.tile[(ty + 8 * i) * 33 + tx] = src[(size_t)(r0 + ty + 8 * i) * NN + c0 + tx];
        __syncthreads();
        #pragma unroll
        for (int i = 0; i < 4; i++)
            dst[(size_t)(c0 + ty + 8 * i) * NN + r0 + tx] = ps.tile[tx * 33 + ty + 8 * i];
    } else if (bid < 3904) {
        int id = bid - 1344;
        const float* W; u16 *Dh, *Dl; int K, N, mat, s, nt;
        if (id < 1280) {
            int seg = id / 320, local = id % 320;
            mat = local >> 5; int rem = local & 31; s = rem >> 2; nt = rem & 3;
            K = 256; N = 256;
            W  = seg == 0 ? Wq : seg == 1 ? Wk : seg == 2 ? Wv : Wc;
            Dh = seg == 0 ? qh : seg == 1 ? kh : seg == 2 ? vh : ch;
            Dl = seg == 0 ? ql : seg == 1 ? kl_ : seg == 2 ? vl : cl;
        } else if (id < 1920) {
            int local = id - 1280;
            mat = local >> 6; int rem = local & 63; s = rem >> 3; nt = rem & 7;
            K = 256; N = 512; W = W1; Dh = f1h; Dl = f1l;
        } else {
            int local = id - 1920;
            mat = local >> 6; int rem = local & 63; s = rem >> 2; nt = rem & 3;
            K = 512; N = 256; W = W2; Dh = f2h; Dl = f2l;
        }
        int kk = t >> 3, nl = (t & 7) * 8;
        const float* p = W + (size_t)mat * K * N + (size_t)(s * 32 + kk) * N + nt * 64 + nl;
        float4 f0 = *(const float4*)p;
        float4 f1v = *(const float4*)(p + 4);
        float fv[8] = {f0.x, f0.y, f0.z, f0.w, f1v.x, f1v.y, f1v.z, f1v.w};
        #pragma unroll
        for (int i = 0; i < 8; i++) bsplit(fv[i], ps.wp.th[(nl + i) * 40 + kk], ps.wp.tl[(nl + i) * 40 + kk]);
        __syncthreads();
        int n = t >> 2, ko = (t & 3) * 8;
        size_t dbase = (size_t)mat * K * N + (size_t)s * N * 32 + (size_t)nt * 64 * 32
                     + (size_t)n * 32 + ko;
        *(us8*)(Dh + dbase) = *(const us8*)&ps.wp.th[n * 40 + ko];
        *(us8*)(Dl + dbase) = *(const us8*)&ps.wp.tl[n * 40 + ko];
    } else {
        // mix constants: c1[lj,h] = sum_e Wedge[e]*Wmix[lj,e,h]; c0 likewise with bedge
        if (t < LAYERS * 2 * H) {
            int lj = t >> 4, h = t & 15;
            float c1 = 0.f, c0 = 0.f;
            for (int e = 0; e < E; e++) {
                float wm = Wmix[(lj * E + e) * H + h];
                c1 += Wedge[e] * wm;
                c0 += bedge[e] * wm;
            }
            c1c0[t] = c1;
            c1c0[160 + t] = c0;
        }
    }
}

// ================= LDS-staged MFMA GEMM, BK=64: 4 slabs / 8 barriers for K=256 =================
// Accumulation order per output element is bitwise-identical to the BK=32 engine
// (same k-32 chunk sequence, same hh/hl/lh order within each chunk).
__device__ __forceinline__ void mfma_gemm(const u16* __restrict__ Ah, const u16* __restrict__ Al,
                                          const u16* __restrict__ Bh, const u16* __restrict__ Bl,
                                          const float* __restrict__ bias, const float* __restrict__ R,
                                          float* __restrict__ Cf, u16* __restrict__ Ch,
                                          u16* __restrict__ Cl, int K, int Ncols, int relu) {
    __shared__ u16 AsH[64 * 72], AsL[64 * 72], BsH[64 * 72], BsL[64 * 72];
    int t = threadIdx.x;
    int lane = t & 63, wave = t >> 6;
    int quad = lane >> 4, l16 = lane & 15;
    int wy = wave >> 1, wx = wave & 1;
    int mBase = blockIdx.x * 64, nBase = blockIdx.y * 64;
    f32x4 acc00 = {0.f, 0.f, 0.f, 0.f}, acc01 = acc00, acc10 = acc00, acc11 = acc00;
    int ar = t >> 2;            // 0..63 (A row / B col)
    int aks = (t & 3) * 16;     // 0,16,32,48 within k-64
    int bkq = (t & 3) * 8;      // 0,8,16,24 within k-32
    const int nslab = K >> 6;   // BK=64
    const u16* apH = Ah + (size_t)(mBase + ar) * K + aks;
    const u16* apL = Al + (size_t)(mBase + ar) * K + aks;
    // B storage: [s32][ntile64][col][k32]; nBase is 64-aligned.
    const size_t sstr = (size_t)Ncols * 32;            // one k-32 storage slab
    size_t bbase = (size_t)(nBase >> 6) * 64 * 32 + (size_t)ar * 32 + bkq;
    const u16* bpH = Bh + bbase;
    const u16* bpL = Bl + bbase;
    us8 rah0 = *(const us8*)apH;       us8 rah1 = *(const us8*)(apH + 8);
    us8 ral0 = *(const us8*)apL;       us8 ral1 = *(const us8*)(apL + 8);
    us8 rbh0 = *(const us8*)bpH;       us8 rbh1 = *(const us8*)(bpH + sstr);
    us8 rbl0 = *(const us8*)bpL;       us8 rbl1 = *(const us8*)(bpL + sstr);
    for (int s = 0; s < nslab; s++) {
        __syncthreads();
        *(us8*)&AsH[ar * 72 + aks] = rah0;      *(us8*)&AsH[ar * 72 + aks + 8] = rah1;
        *(us8*)&AsL[ar * 72 + aks] = ral0;      *(us8*)&AsL[ar * 72 + aks + 8] = ral1;
        *(us8*)&BsH[ar * 72 + bkq] = rbh0;      *(us8*)&BsH[ar * 72 + 32 + bkq] = rbh1;
        *(us8*)&BsL[ar * 72 + bkq] = rbl0;      *(us8*)&BsL[ar * 72 + 32 + bkq] = rbl1;
        __syncthreads();
        if (s + 1 < nslab) {
            rah0 = *(const us8*)(apH + (s + 1) * 64);
            rah1 = *(const us8*)(apH + (s + 1) * 64 + 8);
            ral0 = *(const us8*)(apL + (s + 1) * 64);
            ral1 = *(const us8*)(apL + (s + 1) * 64 + 8);
            const u16* nbH = bpH + (size_t)(2 * (s + 1)) * sstr;
            const u16* nbL = bpL + (size_t)(2 * (s + 1)) * sstr;
            rbh0 = *(const us8*)nbH;  rbh1 = *(const us8*)(nbH + sstr);
            rbl0 = *(const us8*)nbL;  rbl1 = *(const us8*)(nbL + sstr);
        }
        #pragma unroll
        for (int c = 0; c < 2; c++) {
            bfrag a_h0 = *(const bfrag*)&AsH[(wy * 32 + l16) * 72 + c * 32 + quad * 8];
            bfrag a_h1 = *(const bfrag*)&AsH[(wy * 32 + 16 + l16) * 72 + c * 32 + quad * 8];
            bfrag a_l0 = *(const bfrag*)&AsL[(wy * 32 + l16) * 72 + c * 32 + quad * 8];
            bfrag a_l1 = *(const bfrag*)&AsL[(wy * 32 + 16 + l16) * 72 + c * 32 + quad * 8];
            bfrag b_h0 = *(const bfrag*)&BsH[(wx * 32 + l16) * 72 + c * 32 + quad * 8];
            bfrag b_h1 = *(const bfrag*)&BsH[(wx * 32 + 16 + l16) * 72 + c * 32 + quad * 8];
            bfrag b_l0 = *(const bfrag*)&BsL[(wx * 32 + l16) * 72 + c * 32 + quad * 8];
            bfrag b_l1 = *(const bfrag*)&BsL[(wx * 32 + 16 + l16) * 72 + c * 32 + quad * 8];
            acc00 = __builtin_amdgcn_mfma_f32_16x16x32_bf16(a_h0, b_h0, acc00, 0, 0, 0);
            acc01 = __builtin_amdgcn_mfma_f32_16x16x32_bf16(a_h0, b_h1, acc01, 0, 0, 0);
            acc10 = __builtin_amdgcn_mfma_f32_16x16x32_bf16(a_h1, b_h0, acc10, 0, 0, 0);
            acc11 = __builtin_amdgcn_mfma_f32_16x16x32_bf16(a_h1, b_h1, acc11, 0, 0, 0);
            acc00 = __builtin_amdgcn_mfma_f32_16x16x32_bf16(a_h0, b_l0, acc00, 0, 0, 0);
            acc01 = __builtin_amdgcn_mfma_f32_16x16x32_bf16(a_h0, b_l1, acc01, 0, 0, 0);
            acc10 = __builtin_amdgcn_mfma_f32_16x16x32_bf16(a_h1, b_l0, acc10, 0, 0, 0);
            acc11 = __builtin_amdgcn_mfma_f32_16x16x32_bf16(a_h1, b_l1, acc11, 0, 0, 0);
            acc00 = __builtin_amdgcn_mfma_f32_16x16x32_bf16(a_l0, b_h0, acc00, 0, 0, 0);
            acc01 = __builtin_amdgcn_mfma_f32_16x16x32_bf16(a_l0, b_h1, acc01, 0, 0, 0);
            acc10 = __builtin_amdgcn_mfma_f32_16x16x32_bf16(a_l1, b_h0, acc10, 0, 0, 0);
            acc11 = __builtin_amdgcn_mfma_f32_16x16x32_bf16(a_l1, b_h1, acc11, 0, 0, 0);
        }
    }
    int col0 = nBase + wx * 32 + l16;
    int col1 = col0 + 16;
    float bia0 = bias ? bias[col0] : 0.f;
    float bia1 = bias ? bias[col1] : 0.f;
    #pragma unroll
    for (int r = 0; r < 4; r++) {
        int row0 = mBase + wy * 32 + quad * 4 + r;
        int row1 = row0 + 16;
        float v00 = acc00[r] + bia0, v01 = acc01[r] + bia1;
        float v10 = acc10[r] + bia0, v11 = acc11[r] + bia1;
        if (R) {
            v00 += R[(size_t)row0 * Ncols + col0];
            v01 += R[(size_t)row0 * Ncols + col1];
            v10 += R[(size_t)row1 * Ncols + col0];
            v11 += R[(size_t)row1 * Ncols + col1];
        }
        if (relu) {
            v00 = fmaxf(v00, 0.f); v01 = fmaxf(v01, 0.f);
            v10 = fmaxf(v10, 0.f); v11 = fmaxf(v11, 0.f);
        }
        if (Cf) {
            Cf[(size_t)row0 * Ncols + col0] = v00;
            Cf[(size_t)row0 * Ncols + col1] = v01;
            Cf[(size_t)row1 * Ncols + col0] = v10;
            Cf[(size_t)row1 * Ncols + col1] = v11;
        } else {
            u16 h, l;
            bsplit(v00, h, l); Ch[(size_t)row0 * Ncols + col0] = h; Cl[(size_t)row0 * Ncols + col0] = l;
            bsplit(v01, h, l); Ch[(size_t)row0 * Ncols + col1] = h; Cl[(size_t)row0 * Ncols + col1] = l;
            bsplit(v10, h, l); Ch[(size_t)row1 * Ncols + col0] = h; Cl[(size_t)row1 * Ncols + col0] = l;
            bsplit(v11, h, l); Ch[(size_t)row1 * Ncols + col1] = h; Cl[(size_t)row1 * Ncols + col1] = l;
        }
    }
}

// z = j*3 + which(q/k/v); grid (16,4,6)
__global__ __launch_bounds__(256) void k_qkv(const u16* __restrict__ rowh, const u16* __restrict__ rowl,
                                             const u16* __restrict__ colh, const u16* __restrict__ coll,
                                             const u16* __restrict__ WqTh, const u16* __restrict__ WqTl,
                                             const u16* __restrict__ WkTh, const u16* __restrict__ WkTl,
                                             const u16* __restrict__ WvTh, const u16* __restrict__ WvTl,
                                             int lb2,
                                             float* q0, float* k0, float* v0,
                                             float* q1, float* k1, float* v1) {
    int z = blockIdx.z;
    int j = z / 3, w = z % 3;
    const u16* Ah = (w == 0) ? (j ? colh : rowh) : (j ? rowh : colh);
    const u16* Al = (w == 0) ? (j ? coll : rowl) : (j ? rowl : coll);
    const u16* Wh = (w == 0 ? WqTh : (w == 1 ? WkTh : WvTh)) + (size_t)(lb2 + j) * E * E;
    const u16* Wl = (w == 0 ? WqTl : (w == 1 ? WkTl : WvTl)) + (size_t)(lb2 + j) * E * E;
    float* outs[6] = {q0, k0, v0, q1, k1, v1};
    mfma_gemm(Ah, Al, Wh, Wl, nullptr, nullptr, outs[z], nullptr, nullptr, E, E, 0);
}

__global__ __launch_bounds__(256) void k_mgemm(const u16* Ah0, const u16* Al0,
                                               const u16* Ah1, const u16* Al1,
                                               const u16* __restrict__ Bh, const u16* __restrict__ Bl,
                                               int lb2, long wstride,
                                               const float* __restrict__ biasl, int bstride,
                                               const float* R0, const float* R1,
                                               float* Cf0, float* Cf1,
                                               u16* Ch0, u16* Cl0, u16* Ch1, u16* Cl1,
                                               int K, int Ncols, int relu) {
    int j = blockIdx.z;
    mfma_gemm(j ? Ah1 : Ah0, j ? Al1 : Al0,
              Bh + (size_t)(lb2 + j) * wstride, Bl + (size_t)(lb2 + j) * wstride,
              biasl ? biasl + (size_t)j * bstride : nullptr,
              R0 ? (j ? R1 : R0) : nullptr,
              Cf0 ? (j ? Cf1 : Cf0) : nullptr,
              Ch0 ? (j ? Ch1 : Ch0) : nullptr,
              Cl0 ? (j ? Cl1 : Cl0) : nullptr,
              K, Ncols, relu);
}

// ================= fused attention =================
// Round-3 structure (XCD swizzle + q-hoist) + software-pipelined edge loads:
// the 32-iter m-loop is split into 4 blocks of 8; the next block's 8 pedge
// values load into registers while the current block computes, converting a
// serial ~200cyc-per-iter dependent global load into a pipelined stream.
// Per-lane m order and fp accumulation order are bitwise-identical.
__global__ __launch_bounds__(256) void k_attn(const float* __restrict__ q0, const float* __restrict__ k0,
                                              const float* __restrict__ v0, const float* __restrict__ q1,
                                              const float* __restrict__ k1, const float* __restrict__ v1,
                                              const float* __restrict__ data, const float* __restrict__ dataT,
                                              const float* __restrict__ pmin, const float* __restrict__ pmax,
                                              const float* __restrict__ c1c0, int lj_base,
                                              u16* __restrict__ atth0, u16* __restrict__ attl0,
                                              u16* __restrict__ atth1, u16* __restrict__ attl1) {
    // XCD-bijective decode: wgid = ((q8*8 + ng)*8 + r8); siblings share r8.
    int wgid = blockIdx.x;
    int r8 = wgid & 7;
    int qd = wgid >> 3;            // 0..127
    int ng = qd & 7;
    int bhj = r8 * 16 + (qd >> 3); // 0..127, bijective
    int bh = bhj >> 1;
    int j = bhj & 1;
    int b = bh >> 4, h = bh & 15;
    const float* q = j ? q1 : q0;
    const float* k = j ? k1 : k0;
    const float* v = j ? v1 : v0;
    float mn = 1e30f, mx = -1e30f;
    #pragma unroll
    for (int p = 0; p < 16; p++) {
        mn = fminf(mn, pmin[b * 16 + p]);
        mx = fmaxf(mx, pmax[b * 16 + p]);
    }
    float rng = mx - mn;
    if (rng == 0.f) rng = 1.f;
    float inv = 1.f / rng;
    float c1 = c1c0[(lj_base + j) * 16 + h];
    float c0 = c1c0[160 + (lj_base + j) * 16 + h];
    float c1p = inv * c1;
    float c0p = c0 - mn * c1p;

    __shared__ float kl[256 * 20];
    __shared__ float vl[256 * 20];
    int t = threadIdx.x;
    int lane = t & 63, w = t >> 6;
    int r = lane >> 3, ml = lane & 7;
    int n = ng * 32 + w * 8 + r;

    // q loads issued BEFORE staging: latency overlaps the staging drain.
    float qr[16];
    const float* qp = q + ((size_t)(b * NN + n) * E) + h * DD;
    #pragma unroll
    for (int d4 = 0; d4 < 4; d4++) {
        float4 q4 = *(const float4*)(qp + d4 * 4);
        qr[d4 * 4 + 0] = q4.x; qr[d4 * 4 + 1] = q4.y;
        qr[d4 * 4 + 2] = q4.z; qr[d4 * 4 + 3] = q4.w;
    }
    const float* pedge = (j ? dataT : data) + (size_t)b * NN * NN + (size_t)n * NN;

    // first 8 edge values issued before staging as well
    float ped[8];
    #pragma unroll
    for (int ii = 0; ii < 8; ii++) ped[ii] = pedge[ml + 8 * ii];

    {
        int c = t & 3, mb = t >> 2;
        #pragma unroll
        for (int it = 0; it < 4; it++) {
            int m = mb + 64 * it;
            const float* kp = k + ((size_t)(b * NN + m) * E) + h * DD + c * 4;
            const float* vp = v + ((size_t)(b * NN + m) * E) + h * DD + c * 4;
            *(float4*)&kl[m * 20 + c * 4] = *(const float4*)kp;
            *(float4*)&vl[m * 20 + c * 4] = *(const float4*)vp;
        }
    }
    __syncthreads();

    float sum = 0.f;
    float acc[16] = {};
    for (int blk = 0; blk < 4; blk++) {
        float pednxt[8];
        if (blk < 3) {
            #pragma unroll
            for (int ii = 0; ii < 8; ii++) pednxt[ii] = pedge[ml + 8 * (8 * (blk + 1) + ii)];
        }
        #pragma unroll
        for (int ii = 0; ii < 8; ii++) {
            int m = ml + 8 * (blk * 8 + ii);
            float4 ka = *(const float4*)&kl[m * 20 + 0];
            float4 kb = *(const float4*)&kl[m * 20 + 4];
            float4 kc = *(const float4*)&kl[m * 20 + 8];
            float4 kd = *(const float4*)&kl[m * 20 + 12];
            float s0 = qr[0] * ka.x + qr[1] * ka.y + qr[2] * ka.z + qr[3] * ka.w;
            float s1 = qr[4] * kb.x + qr[5] * kb.y + qr[6] * kb.z + qr[7] * kb.w;
            float s2 = qr[8] * kc.x + qr[9] * kc.y + qr[10] * kc.z + qr[11] * kc.w;
            float s3 = qr[12] * kd.x + qr[13] * kd.y + qr[14] * kd.z + qr[15] * kd.w;
            float s = ((s0 + s1) + (s2 + s3)) * 0.25f + ped[ii] * c1p + c0p;
            float e = __expf(s);
            sum += e;
            float4 va = *(const float4*)&vl[m * 20 + 0];
            float4 vb = *(const float4*)&vl[m * 20 + 4];
            float4 vc = *(const float4*)&vl[m * 20 + 8];
            float4 vd = *(const float4*)&vl[m * 20 + 12];
            acc[0] += e * va.x;  acc[1] += e * va.y;  acc[2] += e * va.z;  acc[3] += e * va.w;
            acc[4] += e * vb.x;  acc[5] += e * vb.y;  acc[6] += e * vb.z;  acc[7] += e * vb.w;
            acc[8] += e * vc.x;  acc[9] += e * vc.y;  acc[10] += e * vc.z; acc[11] += e * vc.w;
            acc[12] += e * vd.x; acc[13] += e * vd.y; acc[14] += e * vd.z; acc[15] += e * vd.w;
        }
        if (blk < 3) {
            #pragma unroll
            for (int ii = 0; ii < 8; ii++) ped[ii] = pednxt[ii];
        }
    }
    #pragma unroll
    for (int mask = 1; mask <= 4; mask <<= 1) {
        sum += __shfl_xor(sum, mask);
        #pragma unroll
        for (int d = 0; d < 16; d++) acc[d] += __shfl_xor(acc[d], mask);
    }
    if (ml == 0) {
        float invs = 1.f / sum;
        u16 hh[16], ll[16];
        #pragma unroll
        for (int d = 0; d < 16; d++) bsplit(acc[d] * invs, hh[d], ll[d]);
        size_t base = ((size_t)(b * NN + n) * E) + h * DD;
        u16* oh = (j ? atth1 : atth0) + base;
        u16* ol = (j ? attl1 : attl0) + base;
        *(us8*)oh = *(const us8*)&hh[0];
        *(us8*)(oh + 8) = *(const us8*)&hh[8];
        *(us8*)ol = *(const us8*)&ll[0];
        *(us8*)(ol + 8) = *(const us8*)&ll[8];
    }
}

// ================= instance norm over node dim =================
// grid (B, 2 j, 32 e-chunks of 8), 256 thr; fp32 + bf16 hi/lo outputs.
__global__ __launch_bounds__(256) void k_inorm(const float* __restrict__ Y0, const float* __restrict__ Y1,
                                               const float* __restrict__ wl, const float* __restrict__ bl,
                                               int pstride,
                                               float* Of0, float* Of1,
                                               u16* Oh0, u16* Ol0, u16* Oh1, u16* Ol1,
                                               float* __restrict__ fout) {
    int b = blockIdx.x, j = blockIdx.y;
    int ec = blockIdx.z * 8;
    const float* Y = (j ? Y1 : Y0) + (size_t)b * NN * E;
    float* O = (j ? Of1 : Of0) + (size_t)b * NN * E;
    u16* Oh = (j ? Oh1 : Oh0) + (size_t)b * NN * E;
    u16* Ol = (j ? Ol1 : Ol0) + (size_t)b * NN * E;
    const float* w = wl + (size_t)j * pstride;
    const float* bb = bl + (size_t)j * pstride;
    int t = threadIdx.x;
    int et = t & 7, n0 = t >> 3;
    int e = ec + et;
    float vals[8];
    float s = 0.f, s2 = 0.f;
    #pragma unroll
    for (int kk = 0; kk < 8; kk++) {
        float v = Y[(size_t)(n0 + 32 * kk) * E + e];
        vals[kk] = v;
        s += v;
        s2 += v * v;
    }
    __shared__ float ps[32 * 9], ps2[32 * 9];
    ps[n0 * 9 + et] = s;
    ps2[n0 * 9 + et] = s2;
    __syncthreads();
    float st = 0.f, st2 = 0.f;
    #pragma unroll
    for (int kk = 0; kk < 32; kk++) { st += ps[kk * 9 + et]; st2 += ps2[kk * 9 + et]; }
    float mu = st * (1.f / NN);
    float var = fmaxf(st2 * (1.f / NN) - mu * mu, 0.f);
    float scale = w[e] * rsqrtf(var + 1e-5f);
    float shift = bb[e] - mu * scale;
    #pragma unroll
    for (int kk = 0; kk < 8; kk++) {
        float vv = vals[kk] * scale + shift;
        size_t idx = (size_t)(n0 + 32 * kk) * E + e;
        O[idx] = vv;
        u16 hh, ll;
        bsplit(vv, hh, ll);
        Oh[idx] = hh;
        Ol[idx] = ll;
        if (fout) fout[(size_t)j * (BB * NN * E) + (size_t)b * NN * E + idx] = vv;
    }
}

// ---------------- host ----------------

extern "C" void kernel_launch(void* const* d_in, const int* in_sizes, int n_in,
                              void* d_out, int out_size, void* d_ws, size_t ws_size,
                              hipStream_t stream) {
    const float* data      = (const float*)d_in[0];
    const float* node_rand = (const float*)d_in[1];
    const float* Wnode     = (const float*)d_in[2];
    const float* bnode     = (const float*)d_in[3];
    const float* Wedge     = (const float*)d_in[4];
    const float* bedge     = (const float*)d_in[5];
    const float* Wq        = (const float*)d_in[6];
    const float* Wk        = (const float*)d_in[7];
    const float* Wv        = (const float*)d_in[8];
    const float* Wcomb     = (const float*)d_in[9];
    const float* bcomb     = (const float*)d_in[10];
    const float* n1w       = (const float*)d_in[11];
    const float* n1b       = (const float*)d_in[12];
    const float* W1        = (const float*)d_in[13];
    const float* b1        = (const float*)d_in[14];
    const float* W2        = (const float*)d_in[15];
    const float* b2        = (const float*)d_in[16];
    const float* n2w       = (const float*)d_in[17];
    const float* n2b       = (const float*)d_in[18];
    const float* Wmix      = (const float*)d_in[19];
    float* out = (float*)d_out;  // (row, col) concat

    float* ws = (float*)d_ws;
    const size_t T = (size_t)MROWS * E;      // 262144
    const size_t TF = (size_t)MROWS * FFH;   // 524288
    float* dataT = ws + 0 * T;
    float* row   = ws + 1 * T;
    float* col   = ws + 2 * T;
    float* q0    = ws + 3 * T;
    float* q1    = ws + 4 * T;
    float* k0    = ws + 5 * T;
    float* k1    = ws + 6 * T;
    float* v0    = ws + 7 * T;
    float* v1    = ws + 8 * T;
    float* o1f0  = ws + 9 * T;
    float* o1f1  = ws + 10 * T;
    float* pmin  = ws + 11 * T;
    float* pmax  = pmin + 64;
    float* c1c0  = pmax + 64;
    u16* us = (u16*)(ws + 11 * T + 512);
    auto nxt = [&](size_t n) { u16* p = us; us += n; return p; };
    u16* rowh = nxt(T);  u16* rowl = nxt(T);
    u16* colh = nxt(T);  u16* coll = nxt(T);
    u16* atth0 = nxt(T); u16* attl0 = nxt(T);
    u16* atth1 = nxt(T); u16* attl1 = nxt(T);
    u16* o1h0 = nxt(T);  u16* o1l0 = nxt(T);
    u16* o1h1 = nxt(T);  u16* o1l1 = nxt(T);
    u16* ffhh0 = nxt(TF); u16* ffhl0 = nxt(TF);
    u16* ffhh1 = nxt(TF); u16* ffhl1 = nxt(TF);
    const size_t EE10 = (size_t)10 * E * E;
    const size_t EF10 = (size_t)10 * E * FFH;
    u16* WqTh = nxt(EE10); u16* WqTl = nxt(EE10);
    u16* WkTh = nxt(EE10); u16* WkTl = nxt(EE10);
    u16* WvTh = nxt(EE10); u16* WvTl = nxt(EE10);
    u16* WcTh = nxt(EE10); u16* WcTl = nxt(EE10);
    u16* W1Th = nxt(EF10); u16* W1Tl = nxt(EF10);
    u16* W2Th = nxt(EF10); u16* W2Tl = nxt(EF10);
    // fp32 aliases (liveness-checked, identical to the 461us version)
    float* y0 = q0;   float* y1 = q1;     // comb out (q dead after attn)
    float* y20 = q0;  float* y21 = q1;    // FF2 out (y dead after IN1)

    k_prep<<<3905, 256, 0, stream>>>(data, node_rand, Wnode, bnode,
                                     Wedge, bedge, Wmix,
                                     Wq, Wk, Wv, Wcomb, W1, W2,
                                     pmin, pmax, c1c0,
                                     row, col, rowh, rowl, colh, coll, dataT,
                                     WqTh, WqTl, WkTh, WkTl, WvTh, WvTl,
                                     WcTh, WcTl, W1Th, W1Tl, W2Th, W2Tl);

    for (int l = 0; l < LAYERS; l++) {
        int lb2 = l * 2;
        k_qkv<<<dim3(16, 4, 6), 256, 0, stream>>>(rowh, rowl, colh, coll,
                                                  WqTh, WqTl, WkTh, WkTl, WvTh, WvTl, lb2,
                                                  q0, k0, v0, q1, k1, v1);
        k_attn<<<dim3(1024), 256, 0, stream>>>(q0, k0, v0, q1, k1, v1, data, dataT,
                                               pmin, pmax, c1c0, lb2,
                                               atth0, attl0, atth1, attl1);
        k_mgemm<<<dim3(16, 4, 2), 256, 0, stream>>>(atth0, attl0, atth1, attl1,
                                                    WcTh, WcTl, lb2, (long)E * E,
                                                    bcomb, E,
                                                    row, col, y0, y1,
                                                    nullptr, nullptr, nullptr, nullptr,
                                                    E, E, 0);
        k_inorm<<<dim3(BB, 2, 32), 256, 0, stream>>>(y0, y1,
                                                     n1w + (size_t)lb2 * E, n1b + (size_t)lb2 * E, E,
                                                     o1f0, o1f1, o1h0, o1l0, o1h1, o1l1, nullptr);
        k_mgemm<<<dim3(16, 8, 2), 256, 0, stream>>>(o1h0, o1l0, o1h1, o1l1,
                                                    W1Th, W1Tl, lb2, (long)E * FFH,
                                                    b1, FFH,
                                                    nullptr, nullptr, nullptr, nullptr,
                                                    ffhh0, ffhl0, ffhh1, ffhl1,
                                                    E, FFH, 1);
        k_mgemm<<<dim3(16, 4, 2), 256, 0, stream>>>(ffhh0, ffhl0, ffhh1, ffhl1,
                                                    W2Th, W2Tl, lb2, (long)FFH * E,
                                                    b2, E,
                                                    o1f0, o1f1, q0 /*y20*/, q1 /*y21*/,
                                                    nullptr, nullptr, nullptr, nullptr,
                                                    FFH, E, 0);
        k_inorm<<<dim3(BB, 2, 32), 256, 0, stream>>>(y20, y21,
                                                     n2w + (size_t)lb2 * E, n2b + (size_t)lb2 * E, E,
                                                     row, col, rowh, rowl, colh, coll,
                                                     (l == LAYERS - 1) ? out : nullptr);
    }
}

// Round 6
// 406.769 us; speedup vs baseline: 1.0295x; 1.0295x over previous
//
#include <hip/hip_runtime.h>
#include <hip/hip_bf16.h>

#define E 256
#define H 16
#define DD 16
#define FFH 512
#define LAYERS 5
#define BB 4
#define NN 256
#define MROWS 1024  // B*N

typedef __attribute__((ext_vector_type(8))) short bfrag;
typedef __attribute__((ext_vector_type(4))) float f32x4;
typedef __attribute__((ext_vector_type(8))) unsigned short us8;
typedef unsigned short u16;

__device__ __forceinline__ void bsplit(float v, u16& h, u16& l) {
    unsigned u = __float_as_uint(v);
    u16 hh = (u16)((u + 0x7fffu + ((u >> 16) & 1u)) >> 16);
    float r = v - __uint_as_float((unsigned)hh << 16);
    unsigned u2 = __float_as_uint(r);
    h = hh;
    l = (u16)((u2 + 0x7fffu + ((u2 >> 16) & 1u)) >> 16);
}

// ================= fused prep (minmax | emb | dataT | wprep | mixconst) =================
union PrepS {
    float tile[32 * 33];
    struct { u16 th[64 * 40], tl[64 * 40]; } wp;
    struct { float smin[4], smax[4]; } mm;
};

__global__ __launch_bounds__(256) void k_prep(
    const float* __restrict__ data, const float* __restrict__ node_rand,
    const float* __restrict__ Wnode, const float* __restrict__ bnode,
    const float* __restrict__ Wedge, const float* __restrict__ bedge,
    const float* __restrict__ Wmix,
    const float* __restrict__ Wq, const float* __restrict__ Wk, const float* __restrict__ Wv,
    const float* __restrict__ Wc, const float* __restrict__ W1, const float* __restrict__ W2,
    float* __restrict__ pmin, float* __restrict__ pmax, float* __restrict__ c1c0,
    float* __restrict__ rowb, float* __restrict__ colb,
    u16* rowh, u16* rowl, u16* colh, u16* coll,
    float* __restrict__ dataT,
    u16* qh, u16* ql, u16* kh, u16* kl_, u16* vh, u16* vl,
    u16* ch, u16* cl, u16* f1h, u16* f1l, u16* f2h, u16* f2l) {
    __shared__ PrepS ps;
    int bid = blockIdx.x;
    int t = threadIdx.x;
    if (bid < 64) {
        // minmax stage-1 partials
        int b = bid >> 4, p = bid & 15;
        const float* src = data + (size_t)b * NN * NN + p * 4096;
        float lmin = 1e30f, lmax = -1e30f;
        #pragma unroll
        for (int i = 0; i < 16; i++) {
            float v = src[t + i * 256];
            lmin = fminf(lmin, v);
            lmax = fmaxf(lmax, v);
        }
        #pragma unroll
        for (int off = 32; off; off >>= 1) {
            lmin = fminf(lmin, __shfl_down(lmin, off));
            lmax = fmaxf(lmax, __shfl_down(lmax, off));
        }
        int wid = t >> 6, lane = t & 63;
        if (lane == 0) { ps.mm.smin[wid] = lmin; ps.mm.smax[wid] = lmax; }
        __syncthreads();
        if (t == 0) {
            pmin[b * 16 + p] = fminf(fminf(ps.mm.smin[0], ps.mm.smin[1]), fminf(ps.mm.smin[2], ps.mm.smin[3]));
            pmax[b * 16 + p] = fmaxf(fmaxf(ps.mm.smax[0], ps.mm.smax[1]), fmaxf(ps.mm.smax[2], ps.mm.smax[3]));
        }
    } else if (bid < 1088) {
        int idx = (bid - 64) * 256 + t;
        int bn = idx >> 8, e = idx & 255;
        float v = node_rand[bn] * Wnode[e] + bnode[e];
        rowb[idx] = v;
        colb[idx] = v;
        u16 h, l;
        bsplit(v, h, l);
        rowh[idx] = h; rowl[idx] = l;
        colh[idx] = h; coll[idx] = l;
    } else if (bid < 1344) {
        int local = bid - 1088;
        int bx = local & 7, by = (local >> 3) & 7, b = local >> 6;
        int r0 = by * 32, c0 = bx * 32;
        int tx = t & 31, ty = t >> 5;
        const float* src = data + (size_t)b * NN * NN;
        float* dst = dataT + (size_t)b * NN * NN;
        #pragma unroll
        for (int i = 0; i < 4; i++)
            ps.tile[(ty + 8 * i) * 33 + tx] = src[(size_t)(r0 + ty + 8 * i) * NN + c0 + tx];
        __syncthreads();
        #pragma unroll
        for (int i = 0; i < 4; i++)
            dst[(size_t)(c0 + ty + 8 * i) * NN + r0 + tx] = ps.tile[tx * 33 + ty + 8 * i];
    } else if (bid < 3904) {
        int id = bid - 1344;
        const float* W; u16 *Dh, *Dl; int K, N, mat, s, nt;
        if (id < 1280) {
            int seg = id / 320, local = id % 320;
            mat = local >> 5; int rem = local & 31; s = rem >> 2; nt = rem & 3;
            K = 256; N = 256;
            W  = seg == 0 ? Wq : seg == 1 ? Wk : seg == 2 ? Wv : Wc;
            Dh = seg == 0 ? qh : seg == 1 ? kh : seg == 2 ? vh : ch;
            Dl = seg == 0 ? ql : seg == 1 ? kl_ : seg == 2 ? vl : cl;
        } else if (id < 1920) {
            int local = id - 1280;
            mat = local >> 6; int rem = local & 63; s = rem >> 3; nt = rem & 7;
            K = 256; N = 512; W = W1; Dh = f1h; Dl = f1l;
        } else {
            int local = id - 1920;
            mat = local >> 6; int rem = local & 63; s = rem >> 2; nt = rem & 3;
            K = 512; N = 256; W = W2; Dh = f2h; Dl = f2l;
        }
        int kk = t >> 3, nl = (t & 7) * 8;
        const float* p = W + (size_t)mat * K * N + (size_t)(s * 32 + kk) * N + nt * 64 + nl;
        float4 f0 = *(const float4*)p;
        float4 f1v = *(const float4*)(p + 4);
        float fv[8] = {f0.x, f0.y, f0.z, f0.w, f1v.x, f1v.y, f1v.z, f1v.w};
        #pragma unroll
        for (int i = 0; i < 8; i++) bsplit(fv[i], ps.wp.th[(nl + i) * 40 + kk], ps.wp.tl[(nl + i) * 40 + kk]);
        __syncthreads();
        int n = t >> 2, ko = (t & 3) * 8;
        size_t dbase = (size_t)mat * K * N + (size_t)s * N * 32 + (size_t)nt * 64 * 32
                     + (size_t)n * 32 + ko;
        *(us8*)(Dh + dbase) = *(const us8*)&ps.wp.th[n * 40 + ko];
        *(us8*)(Dl + dbase) = *(const us8*)&ps.wp.tl[n * 40 + ko];
    } else {
        // mix constants: c1[lj,h] = sum_e Wedge[e]*Wmix[lj,e,h]; c0 likewise with bedge
        if (t < LAYERS * 2 * H) {
            int lj = t >> 4, h = t & 15;
            float c1 = 0.f, c0 = 0.f;
            for (int e = 0; e < E; e++) {
                float wm = Wmix[(lj * E + e) * H + h];
                c1 += Wedge[e] * wm;
                c0 += bedge[e] * wm;
            }
            c1c0[t] = c1;
            c1c0[160 + t] = c0;
        }
    }
}

// ================= LDS-staged MFMA GEMM, M=32 x N=64 tile, BK=128 =================
// K=256 -> 2 slabs (4 barriers, was 8); grids double -> full CU coverage.
// Per-output-element k-chunk sequence and hh/hl/lh order are bitwise-identical
// to the BK=64 engine.
__device__ __forceinline__ void mfma_gemm(const u16* __restrict__ Ah, const u16* __restrict__ Al,
                                          const u16* __restrict__ Bh, const u16* __restrict__ Bl,
                                          const float* __restrict__ bias, const float* __restrict__ R,
                                          float* __restrict__ Cf, u16* __restrict__ Ch,
                                          u16* __restrict__ Cl, int K, int Ncols, int relu) {
    __shared__ u16 AsH[32 * 136], AsL[32 * 136], BsH[64 * 136], BsL[64 * 136];
    int t = threadIdx.x;
    int lane = t & 63, wave = t >> 6;
    int quad = lane >> 4, l16 = lane & 15;
    int wy = wave >> 1, wx = wave & 1;
    int mBase = blockIdx.x * 32, nBase = blockIdx.y * 64;
    f32x4 acc0 = {0.f, 0.f, 0.f, 0.f}, acc1 = acc0;
    // A staging: 32 rows x 128 k; thread: row = t>>3, koff = (t&7)*16
    int arow = t >> 3, ak = (t & 7) * 16;
    // B staging: 64 cols x 4 k32-chunks; thread: col = lane, chunk q = wave, 4 parts
    int bcol = lane, bq = wave;
    const int nslab = K >> 7;   // BK=128
    const u16* apH = Ah + (size_t)(mBase + arow) * K + ak;
    const u16* apL = Al + (size_t)(mBase + arow) * K + ak;
    const size_t sstr = (size_t)Ncols * 32;            // one k-32 storage slab
    size_t bbase = (size_t)bq * sstr + (size_t)(nBase + bcol) * 32;
    const u16* bpH = Bh + bbase;
    const u16* bpL = Bl + bbase;
    us8 rah0 = *(const us8*)apH, rah1 = *(const us8*)(apH + 8);
    us8 ral0 = *(const us8*)apL, ral1 = *(const us8*)(apL + 8);
    us8 rbh0 = *(const us8*)(bpH + 0);
    us8 rbh1 = *(const us8*)(bpH + 8);
    us8 rbh2 = *(const us8*)(bpH + 16);
    us8 rbh3 = *(const us8*)(bpH + 24);
    us8 rbl0 = *(const us8*)(bpL + 0);
    us8 rbl1 = *(const us8*)(bpL + 8);
    us8 rbl2 = *(const us8*)(bpL + 16);
    us8 rbl3 = *(const us8*)(bpL + 24);
    for (int s = 0; s < nslab; s++) {
        __syncthreads();
        *(us8*)&AsH[arow * 136 + ak] = rah0;  *(us8*)&AsH[arow * 136 + ak + 8] = rah1;
        *(us8*)&AsL[arow * 136 + ak] = ral0;  *(us8*)&AsL[arow * 136 + ak + 8] = ral1;
        {
            int bb = bcol * 136 + bq * 32;
            *(us8*)&BsH[bb + 0] = rbh0;  *(us8*)&BsH[bb + 8] = rbh1;
            *(us8*)&BsH[bb + 16] = rbh2; *(us8*)&BsH[bb + 24] = rbh3;
            *(us8*)&BsL[bb + 0] = rbl0;  *(us8*)&BsL[bb + 8] = rbl1;
            *(us8*)&BsL[bb + 16] = rbl2; *(us8*)&BsL[bb + 24] = rbl3;
        }
        __syncthreads();
        if (s + 1 < nslab) {
            rah0 = *(const us8*)(apH + (s + 1) * 128);
            rah1 = *(const us8*)(apH + (s + 1) * 128 + 8);
            ral0 = *(const us8*)(apL + (s + 1) * 128);
            ral1 = *(const us8*)(apL + (s + 1) * 128 + 8);
            const u16* nbH = bpH + (size_t)(4 * (s + 1)) * sstr;
            const u16* nbL = bpL + (size_t)(4 * (s + 1)) * sstr;
            rbh0 = *(const us8*)(nbH + 0);  rbh1 = *(const us8*)(nbH + 8);
            rbh2 = *(const us8*)(nbH + 16); rbh3 = *(const us8*)(nbH + 24);
            rbl0 = *(const us8*)(nbL + 0);  rbl1 = *(const us8*)(nbL + 8);
            rbl2 = *(const us8*)(nbL + 16); rbl3 = *(const us8*)(nbL + 24);
        }
        #pragma unroll
        for (int c = 0; c < 4; c++) {
            bfrag a_h = *(const bfrag*)&AsH[(wy * 16 + l16) * 136 + c * 32 + quad * 8];
            bfrag a_l = *(const bfrag*)&AsL[(wy * 16 + l16) * 136 + c * 32 + quad * 8];
            bfrag b_h0 = *(const bfrag*)&BsH[(wx * 32 + l16) * 136 + c * 32 + quad * 8];
            bfrag b_h1 = *(const bfrag*)&BsH[(wx * 32 + 16 + l16) * 136 + c * 32 + quad * 8];
            bfrag b_l0 = *(const bfrag*)&BsL[(wx * 32 + l16) * 136 + c * 32 + quad * 8];
            bfrag b_l1 = *(const bfrag*)&BsL[(wx * 32 + 16 + l16) * 136 + c * 32 + quad * 8];
            acc0 = __builtin_amdgcn_mfma_f32_16x16x32_bf16(a_h, b_h0, acc0, 0, 0, 0);
            acc1 = __builtin_amdgcn_mfma_f32_16x16x32_bf16(a_h, b_h1, acc1, 0, 0, 0);
            acc0 = __builtin_amdgcn_mfma_f32_16x16x32_bf16(a_h, b_l0, acc0, 0, 0, 0);
            acc1 = __builtin_amdgcn_mfma_f32_16x16x32_bf16(a_h, b_l1, acc1, 0, 0, 0);
            acc0 = __builtin_amdgcn_mfma_f32_16x16x32_bf16(a_l, b_h0, acc0, 0, 0, 0);
            acc1 = __builtin_amdgcn_mfma_f32_16x16x32_bf16(a_l, b_h1, acc1, 0, 0, 0);
        }
    }
    int col0 = nBase + wx * 32 + l16;
    int col1 = col0 + 16;
    float bia0 = bias ? bias[col0] : 0.f;
    float bia1 = bias ? bias[col1] : 0.f;
    #pragma unroll
    for (int r = 0; r < 4; r++) {
        int row0 = mBase + wy * 16 + quad * 4 + r;
        float v0 = acc0[r] + bia0, v1 = acc1[r] + bia1;
        if (R) {
            v0 += R[(size_t)row0 * Ncols + col0];
            v1 += R[(size_t)row0 * Ncols + col1];
        }
        if (relu) {
            v0 = fmaxf(v0, 0.f); v1 = fmaxf(v1, 0.f);
        }
        if (Cf) {
            Cf[(size_t)row0 * Ncols + col0] = v0;
            Cf[(size_t)row0 * Ncols + col1] = v1;
        } else {
            u16 h, l;
            bsplit(v0, h, l); Ch[(size_t)row0 * Ncols + col0] = h; Cl[(size_t)row0 * Ncols + col0] = l;
            bsplit(v1, h, l); Ch[(size_t)row0 * Ncols + col1] = h; Cl[(size_t)row0 * Ncols + col1] = l;
        }
    }
}

// z = j*3 + which(q/k/v); grid (32,4,6)
__global__ __launch_bounds__(256) void k_qkv(const u16* __restrict__ rowh, const u16* __restrict__ rowl,
                                             const u16* __restrict__ colh, const u16* __restrict__ coll,
                                             const u16* __restrict__ WqTh, const u16* __restrict__ WqTl,
                                             const u16* __restrict__ WkTh, const u16* __restrict__ WkTl,
                                             const u16* __restrict__ WvTh, const u16* __restrict__ WvTl,
                                             int lb2,
                                             float* q0, float* k0, float* v0,
                                             float* q1, float* k1, float* v1) {
    int z = blockIdx.z;
    int j = z / 3, w = z % 3;
    const u16* Ah = (w == 0) ? (j ? colh : rowh) : (j ? rowh : colh);
    const u16* Al = (w == 0) ? (j ? coll : rowl) : (j ? rowl : coll);
    const u16* Wh = (w == 0 ? WqTh : (w == 1 ? WkTh : WvTh)) + (size_t)(lb2 + j) * E * E;
    const u16* Wl = (w == 0 ? WqTl : (w == 1 ? WkTl : WvTl)) + (size_t)(lb2 + j) * E * E;
    float* outs[6] = {q0, k0, v0, q1, k1, v1};
    mfma_gemm(Ah, Al, Wh, Wl, nullptr, nullptr, outs[z], nullptr, nullptr, E, E, 0);
}

__global__ __launch_bounds__(256) void k_mgemm(const u16* Ah0, const u16* Al0,
                                               const u16* Ah1, const u16* Al1,
                                               const u16* __restrict__ Bh, const u16* __restrict__ Bl,
                                               int lb2, long wstride,
                                               const float* __restrict__ biasl, int bstride,
                                               const float* R0, const float* R1,
                                               float* Cf0, float* Cf1,
                                               u16* Ch0, u16* Cl0, u16* Ch1, u16* Cl1,
                                               int K, int Ncols, int relu) {
    int j = blockIdx.z;
    mfma_gemm(j ? Ah1 : Ah0, j ? Al1 : Al0,
              Bh + (size_t)(lb2 + j) * wstride, Bl + (size_t)(lb2 + j) * wstride,
              biasl ? biasl + (size_t)j * bstride : nullptr,
              R0 ? (j ? R1 : R0) : nullptr,
              Cf0 ? (j ? Cf1 : Cf0) : nullptr,
              Ch0 ? (j ? Ch1 : Ch0) : nullptr,
              Cl0 ? (j ? Cl1 : Cl0) : nullptr,
              K, Ncols, relu);
}

// ================= fused attention =================
// Round-3/4 proven structure: XCD-bijective swizzle + q-hoist.
__global__ __launch_bounds__(256) void k_attn(const float* __restrict__ q0, const float* __restrict__ k0,
                                              const float* __restrict__ v0, const float* __restrict__ q1,
                                              const float* __restrict__ k1, const float* __restrict__ v1,
                                              const float* __restrict__ data, const float* __restrict__ dataT,
                                              const float* __restrict__ pmin, const float* __restrict__ pmax,
                                              const float* __restrict__ c1c0, int lj_base,
                                              u16* __restrict__ atth0, u16* __restrict__ attl0,
                                              u16* __restrict__ atth1, u16* __restrict__ attl1) {
    // XCD-bijective decode: wgid = ((q8*8 + ng)*8 + r8); siblings share r8.
    int wgid = blockIdx.x;
    int r8 = wgid & 7;
    int qd = wgid >> 3;            // 0..127
    int ng = qd & 7;
    int bhj = r8 * 16 + (qd >> 3); // 0..127, bijective
    int bh = bhj >> 1;
    int j = bhj & 1;
    int b = bh >> 4, h = bh & 15;
    const float* q = j ? q1 : q0;
    const float* k = j ? k1 : k0;
    const float* v = j ? v1 : v0;
    float mn = 1e30f, mx = -1e30f;
    #pragma unroll
    for (int p = 0; p < 16; p++) {
        mn = fminf(mn, pmin[b * 16 + p]);
        mx = fmaxf(mx, pmax[b * 16 + p]);
    }
    float rng = mx - mn;
    if (rng == 0.f) rng = 1.f;
    float inv = 1.f / rng;
    float c1 = c1c0[(lj_base + j) * 16 + h];
    float c0 = c1c0[160 + (lj_base + j) * 16 + h];
    float c1p = inv * c1;
    float c0p = c0 - mn * c1p;

    __shared__ float kl[256 * 20];
    __shared__ float vl[256 * 20];
    int t = threadIdx.x;
    int lane = t & 63, w = t >> 6;
    int r = lane >> 3, ml = lane & 7;
    int n = ng * 32 + w * 8 + r;

    // q loads issued BEFORE staging: latency overlaps the staging drain.
    float qr[16];
    const float* qp = q + ((size_t)(b * NN + n) * E) + h * DD;
    #pragma unroll
    for (int d4 = 0; d4 < 4; d4++) {
        float4 q4 = *(const float4*)(qp + d4 * 4);
        qr[d4 * 4 + 0] = q4.x; qr[d4 * 4 + 1] = q4.y;
        qr[d4 * 4 + 2] = q4.z; qr[d4 * 4 + 3] = q4.w;
    }

    {
        int c = t & 3, mb = t >> 2;
        #pragma unroll
        for (int it = 0; it < 4; it++) {
            int m = mb + 64 * it;
            const float* kp = k + ((size_t)(b * NN + m) * E) + h * DD + c * 4;
            const float* vp = v + ((size_t)(b * NN + m) * E) + h * DD + c * 4;
            *(float4*)&kl[m * 20 + c * 4] = *(const float4*)kp;
            *(float4*)&vl[m * 20 + c * 4] = *(const float4*)vp;
        }
    }
    __syncthreads();

    const float* pedge = (j ? dataT : data) + (size_t)b * NN * NN + (size_t)n * NN;

    float sum = 0.f;
    float acc[16] = {};
    for (int i = 0; i < 32; i++) {
        int m = ml + 8 * i;
        float4 ka = *(const float4*)&kl[m * 20 + 0];
        float4 kb = *(const float4*)&kl[m * 20 + 4];
        float4 kc = *(const float4*)&kl[m * 20 + 8];
        float4 kd = *(const float4*)&kl[m * 20 + 12];
        float s0 = qr[0] * ka.x + qr[1] * ka.y + qr[2] * ka.z + qr[3] * ka.w;
        float s1 = qr[4] * kb.x + qr[5] * kb.y + qr[6] * kb.z + qr[7] * kb.w;
        float s2 = qr[8] * kc.x + qr[9] * kc.y + qr[10] * kc.z + qr[11] * kc.w;
        float s3 = qr[12] * kd.x + qr[13] * kd.y + qr[14] * kd.z + qr[15] * kd.w;
        float s = ((s0 + s1) + (s2 + s3)) * 0.25f + pedge[m] * c1p + c0p;
        float e = __expf(s);
        sum += e;
        float4 va = *(const float4*)&vl[m * 20 + 0];
        float4 vb = *(const float4*)&vl[m * 20 + 4];
        float4 vc = *(const float4*)&vl[m * 20 + 8];
        float4 vd = *(const float4*)&vl[m * 20 + 12];
        acc[0] += e * va.x;  acc[1] += e * va.y;  acc[2] += e * va.z;  acc[3] += e * va.w;
        acc[4] += e * vb.x;  acc[5] += e * vb.y;  acc[6] += e * vb.z;  acc[7] += e * vb.w;
        acc[8] += e * vc.x;  acc[9] += e * vc.y;  acc[10] += e * vc.z; acc[11] += e * vc.w;
        acc[12] += e * vd.x; acc[13] += e * vd.y; acc[14] += e * vd.z; acc[15] += e * vd.w;
    }
    #pragma unroll
    for (int mask = 1; mask <= 4; mask <<= 1) {
        sum += __shfl_xor(sum, mask);
        #pragma unroll
        for (int d = 0; d < 16; d++) acc[d] += __shfl_xor(acc[d], mask);
    }
    if (ml == 0) {
        float invs = 1.f / sum;
        u16 hh[16], ll[16];
        #pragma unroll
        for (int d = 0; d < 16; d++) bsplit(acc[d] * invs, hh[d], ll[d]);
        size_t base = ((size_t)(b * NN + n) * E) + h * DD;
        u16* oh = (j ? atth1 : atth0) + base;
        u16* ol = (j ? attl1 : attl0) + base;
        *(us8*)oh = *(const us8*)&hh[0];
        *(us8*)(oh + 8) = *(const us8*)&hh[8];
        *(us8*)ol = *(const us8*)&ll[0];
        *(us8*)(ol + 8) = *(const us8*)&ll[8];
    }
}

// ================= instance norm over node dim =================
// grid (B, 2 j, 32 e-chunks of 8), 256 thr; fp32 + bf16 hi/lo outputs.
__global__ __launch_bounds__(256) void k_inorm(const float* __restrict__ Y0, const float* __restrict__ Y1,
                                               const float* __restrict__ wl, const float* __restrict__ bl,
                                               int pstride,
                                               float* Of0, float* Of1,
                                               u16* Oh0, u16* Ol0, u16* Oh1, u16* Ol1,
                                               float* __restrict__ fout) {
    int b = blockIdx.x, j = blockIdx.y;
    int ec = blockIdx.z * 8;
    const float* Y = (j ? Y1 : Y0) + (size_t)b * NN * E;
    float* O = (j ? Of1 : Of0) + (size_t)b * NN * E;
    u16* Oh = (j ? Oh1 : Oh0) + (size_t)b * NN * E;
    u16* Ol = (j ? Ol1 : Ol0) + (size_t)b * NN * E;
    const float* w = wl + (size_t)j * pstride;
    const float* bb = bl + (size_t)j * pstride;
    int t = threadIdx.x;
    int et = t & 7, n0 = t >> 3;
    int e = ec + et;
    float vals[8];
    float s = 0.f, s2 = 0.f;
    #pragma unroll
    for (int kk = 0; kk < 8; kk++) {
        float v = Y[(size_t)(n0 + 32 * kk) * E + e];
        vals[kk] = v;
        s += v;
        s2 += v * v;
    }
    __shared__ float ps[32 * 9], ps2[32 * 9];
    ps[n0 * 9 + et] = s;
    ps2[n0 * 9 + et] = s2;
    __syncthreads();
    float st = 0.f, st2 = 0.f;
    #pragma unroll
    for (int kk = 0; kk < 32; kk++) { st += ps[kk * 9 + et]; st2 += ps2[kk * 9 + et]; }
    float mu = st * (1.f / NN);
    float var = fmaxf(st2 * (1.f / NN) - mu * mu, 0.f);
    float scale = w[e] * rsqrtf(var + 1e-5f);
    float shift = bb[e] - mu * scale;
    #pragma unroll
    for (int kk = 0; kk < 8; kk++) {
        float vv = vals[kk] * scale + shift;
        size_t idx = (size_t)(n0 + 32 * kk) * E + e;
        O[idx] = vv;
        u16 hh, ll;
        bsplit(vv, hh, ll);
        Oh[idx] = hh;
        Ol[idx] = ll;
        if (fout) fout[(size_t)j * (BB * NN * E) + (size_t)b * NN * E + idx] = vv;
    }
}

// ---------------- host ----------------

extern "C" void kernel_launch(void* const* d_in, const int* in_sizes, int n_in,
                              void* d_out, int out_size, void* d_ws, size_t ws_size,
                              hipStream_t stream) {
    const float* data      = (const float*)d_in[0];
    const float* node_rand = (const float*)d_in[1];
    const float* Wnode     = (const float*)d_in[2];
    const float* bnode     = (const float*)d_in[3];
    const float* Wedge     = (const float*)d_in[4];
    const float* bedge     = (const float*)d_in[5];
    const float* Wq        = (const float*)d_in[6];
    const float* Wk        = (const float*)d_in[7];
    const float* Wv        = (const float*)d_in[8];
    const float* Wcomb     = (const float*)d_in[9];
    const float* bcomb     = (const float*)d_in[10];
    const float* n1w       = (const float*)d_in[11];
    const float* n1b       = (const float*)d_in[12];
    const float* W1        = (const float*)d_in[13];
    const float* b1        = (const float*)d_in[14];
    const float* W2        = (const float*)d_in[15];
    const float* b2        = (const float*)d_in[16];
    const float* n2w       = (const float*)d_in[17];
    const float* n2b       = (const float*)d_in[18];
    const float* Wmix      = (const float*)d_in[19];
    float* out = (float*)d_out;  // (row, col) concat

    float* ws = (float*)d_ws;
    const size_t T = (size_t)MROWS * E;      // 262144
    const size_t TF = (size_t)MROWS * FFH;   // 524288
    float* dataT = ws + 0 * T;
    float* row   = ws + 1 * T;
    float* col   = ws + 2 * T;
    float* q0    = ws + 3 * T;
    float* q1    = ws + 4 * T;
    float* k0    = ws + 5 * T;
    float* k1    = ws + 6 * T;
    float* v0    = ws + 7 * T;
    float* v1    = ws + 8 * T;
    float* o1f0  = ws + 9 * T;
    float* o1f1  = ws + 10 * T;
    float* pmin  = ws + 11 * T;
    float* pmax  = pmin + 64;
    float* c1c0  = pmax + 64;
    u16* us = (u16*)(ws + 11 * T + 512);
    auto nxt = [&](size_t n) { u16* p = us; us += n; return p; };
    u16* rowh = nxt(T);  u16* rowl = nxt(T);
    u16* colh = nxt(T);  u16* coll = nxt(T);
    u16* atth0 = nxt(T); u16* attl0 = nxt(T);
    u16* atth1 = nxt(T); u16* attl1 = nxt(T);
    u16* o1h0 = nxt(T);  u16* o1l0 = nxt(T);
    u16* o1h1 = nxt(T);  u16* o1l1 = nxt(T);
    u16* ffhh0 = nxt(TF); u16* ffhl0 = nxt(TF);
    u16* ffhh1 = nxt(TF); u16* ffhl1 = nxt(TF);
    const size_t EE10 = (size_t)10 * E * E;
    const size_t EF10 = (size_t)10 * E * FFH;
    u16* WqTh = nxt(EE10); u16* WqTl = nxt(EE10);
    u16* WkTh = nxt(EE10); u16* WkTl = nxt(EE10);
    u16* WvTh = nxt(EE10); u16* WvTl = nxt(EE10);
    u16* WcTh = nxt(EE10); u16* WcTl = nxt(EE10);
    u16* W1Th = nxt(EF10); u16* W1Tl = nxt(EF10);
    u16* W2Th = nxt(EF10); u16* W2Tl = nxt(EF10);
    // fp32 aliases (liveness-checked, identical to the 461us version)
    float* y0 = q0;   float* y1 = q1;     // comb out (q dead after attn)
    float* y20 = q0;  float* y21 = q1;    // FF2 out (y dead after IN1)

    k_prep<<<3905, 256, 0, stream>>>(data, node_rand, Wnode, bnode,
                                     Wedge, bedge, Wmix,
                                     Wq, Wk, Wv, Wcomb, W1, W2,
                                     pmin, pmax, c1c0,
                                     row, col, rowh, rowl, colh, coll, dataT,
                                     WqTh, WqTl, WkTh, WkTl, WvTh, WvTl,
                                     WcTh, WcTl, W1Th, W1Tl, W2Th, W2Tl);

    for (int l = 0; l < LAYERS; l++) {
        int lb2 = l * 2;
        k_qkv<<<dim3(32, 4, 6), 256, 0, stream>>>(rowh, rowl, colh, coll,
                                                  WqTh, WqTl, WkTh, WkTl, WvTh, WvTl, lb2,
                                                  q0, k0, v0, q1, k1, v1);
        k_attn<<<dim3(1024), 256, 0, stream>>>(q0, k0, v0, q1, k1, v1, data, dataT,
                                               pmin, pmax, c1c0, lb2,
                                               atth0, attl0, atth1, attl1);
        k_mgemm<<<dim3(32, 4, 2), 256, 0, stream>>>(atth0, attl0, atth1, attl1,
                                                    WcTh, WcTl, lb2, (long)E * E,
                                                    bcomb, E,
                                                    row, col, y0, y1,
                                                    nullptr, nullptr, nullptr, nullptr,
                                                    E, E, 0);
        k_inorm<<<dim3(BB, 2, 32), 256, 0, stream>>>(y0, y1,
                                                     n1w + (size_t)lb2 * E, n1b + (size_t)lb2 * E, E,
                                                     o1f0, o1f1, o1h0, o1l0, o1h1, o1l1, nullptr);
        k_mgemm<<<dim3(32, 8, 2), 256, 0, stream>>>(o1h0, o1l0, o1h1, o1l1,
                                                    W1Th, W1Tl, lb2, (long)E * FFH,
                                                    b1, FFH,
                                                    nullptr, nullptr, nullptr, nullptr,
                                                    ffhh0, ffhl0, ffhh1, ffhl1,
                                                    E, FFH, 1);
        k_mgemm<<<dim3(32, 4, 2), 256, 0, stream>>>(ffhh0, ffhl0, ffhh1, ffhl1,
                                                    W2Th, W2Tl, lb2, (long)FFH * E,
                                                    b2, E,
                                                    o1f0, o1f1, q0 /*y20*/, q1 /*y21*/,
                                                    nullptr, nullptr, nullptr, nullptr,
                                                    FFH, E, 0);
        k_inorm<<<dim3(BB, 2, 32), 256, 0, stream>>>(y20, y21,
                                                     n2w + (size_t)lb2 * E, n2b + (size_t)lb2 * E, E,
                                                     row, col, rowh, rowl, colh, coll,
                                                     (l == LAYERS - 1) ? out : nullptr);
    }
}